// Round 17
// baseline (471.812 us; speedup 1.0000x reference)
//
#include <hip/hip_runtime.h>
#include <hip/hip_bf16.h>
#include <math.h>

// ---------------------------------------------------------------------------
// GINE x3 + global_add_pool + Bayesian head.
// Round 17: prep-chain surgery — register-serial single-pass scan (2 barriers),
// cursor zeroing folded into xprep (memset dispatch dropped), xprep first.
// Compute kernels identical to R16.
// ---------------------------------------------------------------------------

#define THREADS 256

typedef __attribute__((ext_vector_type(8))) short bf16x8;
typedef __attribute__((ext_vector_type(4))) float f32x4;

__device__ __forceinline__ unsigned short f2bf(float x) {
    __hip_bfloat16 h = __float2bfloat16(x);
    return __builtin_bit_cast(unsigned short, h);
}
__device__ __forceinline__ float bflo(unsigned u) {
    return __builtin_bit_cast(float, u << 16);
}
__device__ __forceinline__ float bfhi(unsigned u) {
    return __builtin_bit_cast(float, u & 0xffff0000u);
}
__device__ __forceinline__ float bf2f(unsigned short u) {
    return __builtin_bit_cast(float, (unsigned)u << 16);
}
__device__ __forceinline__ unsigned pk(float a, float b) {
    return (unsigned)f2bf(a) | ((unsigned)f2bf(b) << 16);
}

// ---------------- CSR build: histogram of dst
__global__ __launch_bounds__(THREADS) void hist_kernel(
    const int* __restrict__ ei, int* __restrict__ deg, int E)
{
    int e = blockIdx.x * THREADS + threadIdx.x;
    if (e < E) atomicAdd(&deg[ei[E + e]], 1);
}

// ---------------- CSR build: register-serial scan, 2 barriers.
// Each thread owns a contiguous run; zeroes deg (=cursor) in the write pass.
__global__ __launch_bounds__(1024) void scan_kernel(
    int* __restrict__ deg, int* __restrict__ rowptr, int n)
{
    __shared__ int wsum[16];
    const int t    = threadIdx.x;
    const int lane = t & 63, wv = t >> 6;
    const int chunk = (n + 1023) >> 10;
    const int beg = t * chunk;
    const int end = (beg + chunk < n) ? (beg + chunk) : n;

    // pass 1: per-thread sum
    int s = 0;
    for (int i = beg; i < end; ++i) s += deg[i];

    // block exclusive scan of the 1024 thread sums
    int incl = s;
#pragma unroll
    for (int off = 1; off < 64; off <<= 1) {
        int u = __shfl_up(incl, off, 64);
        if (lane >= off) incl += u;
    }
    if (lane == 63) wsum[wv] = incl;
    __syncthreads();
    if (wv == 0) {
        int v = (lane < 16) ? wsum[lane] : 0;
#pragma unroll
        for (int off = 1; off < 16; off <<= 1) {
            int u = __shfl_up(v, off, 64);
            if (lane >= off) v += u;
        }
        if (lane < 16) wsum[lane] = v;   // inclusive wave sums
    }
    __syncthreads();
    int excl = ((wv == 0) ? 0 : wsum[wv - 1]) + incl - s;

    // pass 2: write rowptr, zero deg
    int run = excl;
    for (int i = beg; i < end; ++i) {
        int v = deg[i];
        deg[i] = 0;
        run += v;
        rowptr[i + 1] = run;
    }
    if (t == 0) rowptr[0] = 0;
}

// ---------------- CSR build: scatter edges into slots + ea16 (fused easort)
__global__ __launch_bounds__(THREADS) void fill_kernel(
    const int* __restrict__ ei, const int* __restrict__ rowptr,
    int* __restrict__ cursor, int* __restrict__ csr_src,
    int* __restrict__ csr_dst, const float* __restrict__ edge_attr,
    unsigned short* __restrict__ ea16, int E)
{
    int e = blockIdx.x * THREADS + threadIdx.x;
    if (e >= E) return;
    int s = ei[e], d = ei[E + e];
    int pos  = atomicAdd(&cursor[d], 1);
    int slot = rowptr[d] + pos;
    csr_src[slot] = s;
    csr_dst[slot] = d;
    const float4* a = (const float4*)(edge_attr + (size_t)e * 16);
    float4 a0 = a[0], a1 = a[1], a2 = a[2], a3 = a[3];
    uint4* dst = (uint4*)(ea16 + (size_t)slot * 16);
    dst[0] = make_uint4(pk(a0.x, a0.y), pk(a0.z, a0.w), pk(a1.x, a1.y), pk(a1.z, a1.w));
    dst[1] = make_uint4(pk(a2.x, a2.y), pk(a2.z, a2.w), pk(a3.x, a3.y), pk(a3.z, a3.w));
}

// ---------------- x -> bf16 copy; zeroes aggbf, hg, AND cursor
__global__ __launch_bounds__(THREADS) void xprep_kernel(
    const float* __restrict__ x, unsigned short* __restrict__ xbf, int n4,
    uint4* __restrict__ aggz, int nAgg4,
    float4* __restrict__ hgz, int nHg4,
    uint4* __restrict__ curz, int nCur4)
{
    int i = blockIdx.x * THREADS + threadIdx.x;
    if (i < n4) {
        float4 v = ((const float4*)x)[i];
        uint2 p;
        p.x = pk(v.x, v.y);
        p.y = pk(v.z, v.w);
        ((uint2*)xbf)[i] = p;
    }
    if (i < nAgg4) aggz[i] = make_uint4(0, 0, 0, 0);
    if (i < nHg4)  hgz[i]  = make_float4(0.f, 0.f, 0.f, 0.f);
    if (i < nCur4) curz[i] = make_uint4(0, 0, 0, 0);
}

// ---------------- unified weight prep
struct PrepArgs {
    const float* W[6]; unsigned short* Wt[6]; int K[6];
    const float* mu; const float* ls; const float* eps; float* w1buf;
    const float* We[3]; unsigned short* Wp[3]; int D[3];
};
__global__ __launch_bounds__(THREADS) void prep_kernel(PrepArgs a)
{
    __shared__ float tile[32][33];
    const int z = blockIdx.z;
    const int t = threadIdx.x;

    if (z < 6) {
        const int K = a.K[z];
        const int kb = blockIdx.x * 32;
        if (kb >= K) return;
        const float* W = a.W[z];
        unsigned short* Wt = a.Wt[z];
        const int nb = blockIdx.y * 32;
        const int tx = t & 31, ty = t >> 5;
#pragma unroll
        for (int i = ty; i < 32; i += 8)
            tile[i][tx] = W[(size_t)(kb + i) * 256 + nb + tx];
        __syncthreads();
#pragma unroll
        for (int i = ty; i < 32; i += 8)
            Wt[(size_t)(nb + i) * K + kb + tx] = f2bf(tile[tx][i]);
    } else if (z == 6) {
        int blk = blockIdx.x + blockIdx.y * 8;         // 0..63
#pragma unroll
        for (int c = 0; c < 4; c++) {
            int i = blk * THREADS + t + c * 16384;     // covers 65536
            a.w1buf[i] = a.mu[i] + expf(a.ls[i]) * a.eps[i];
        }
    } else {
        int l = blockIdx.x + blockIdx.y * 8;
        if (l >= 3) return;
        int D = a.D[l];
        if (t >= D) return;
        const float* We = a.We[l];
        unsigned short* Wp = a.Wp[l];
#pragma unroll
        for (int k = 0; k < 16; k++) Wp[t * 32 + k] = f2bf(We[k * D + t]);
#pragma unroll
        for (int k = 16; k < 32; k++) Wp[t * 32 + k] = 0;
    }
}

// ---------------- fused MFMA aggregation (2 feats/lane config)
template<int D>
__global__ __launch_bounds__(THREADS) void edge_agg_kernel(
    const unsigned short* __restrict__ hbf,   // [N][D] bf16
    const unsigned short* __restrict__ ea16,  // [E][16] bf16, CSR order
    const int* __restrict__ csr_src,          // [E]
    const int* __restrict__ csr_dst,          // [E] (non-decreasing)
    const unsigned short* __restrict__ Wtp,   // [D][32] bf16, k>=16 zero
    const float* __restrict__ be,             // [D]
    unsigned short* __restrict__ agg,         // [N][D] bf16, pre-zeroed
    int E)
{
    constexpr int EPB = (D == 128) ? 64 : 32;    // edges per block
    constexpr int LDF = D + 8;                   // padded LDS stride (shorts)
    __shared__ unsigned short msg[EPB * LDF];
    __shared__ int src_s[EPB];
    __shared__ int dst_x[EPB + 2];               // dst of edges e0-1 .. e0+EPB

    const int t    = threadIdx.x;
    const int e0   = blockIdx.x * EPB;
    const int lane = t & 63, wid = t >> 6;
    const int l15  = lane & 15, lgr = lane >> 4;

    for (int i = t; i < EPB; i += THREADS) {
        int e = e0 + i;
        src_s[i] = (e < E) ? csr_src[e] : 0;
    }
    for (int i = t; i < EPB + 2; i += THREADS) {
        int e = e0 + i - 1;
        dst_x[i] = (e < 0) ? -2 : ((e < E) ? csr_dst[e] : -1);
    }

    const int fb = (D == 128) ? (wid & 1) * 64 : wid * 64;   // feature base
    const int eb = (D == 128) ? (wid >> 1) * 32 : 0;         // edge base

    bf16x8 af[4];
#pragma unroll
    for (int mf = 0; mf < 4; mf++)
        af[mf] = *(const bf16x8*)(Wtp + (unsigned)(fb + mf * 16 + l15) * 32 + lgr * 8);

    f32x4 acc[4][2];
#pragma unroll
    for (int mf = 0; mf < 4; mf++) {
        int fpos = fb + mf * 16 + lgr * 4;
        float4 bv4 = *(const float4*)(be + fpos);
        f32x4 binit = (f32x4){bv4.x, bv4.y, bv4.z, bv4.w};
        acc[mf][0] = binit;
        acc[mf][1] = binit;
    }

#pragma unroll
    for (int nf = 0; nf < 2; nf++) {
        int er = e0 + eb + nf * 16 + l15;
        bf16x8 bv = (bf16x8){0, 0, 0, 0, 0, 0, 0, 0};
        if (lgr < 2 && er < E)
            bv = *(const bf16x8*)(ea16 + (size_t)er * 16 + lgr * 8);
#pragma unroll
        for (int mf = 0; mf < 4; mf++)
            acc[mf][nf] = __builtin_amdgcn_mfma_f32_16x16x32_bf16(
                af[mf], bv, acc[mf][nf], 0, 0, 0);
    }

#pragma unroll
    for (int nf = 0; nf < 2; nf++) {
        int edge = eb + nf * 16 + l15;
#pragma unroll
        for (int mf = 0; mf < 4; mf++) {
            int fpos = fb + mf * 16 + lgr * 4;
            f32x4 v = acc[mf][nf];
            uint2 p;
            p.x = pk(v[0], v[1]);
            p.y = pk(v[2], v[3]);
            *(uint2*)(&msg[edge * LDF + fpos]) = p;
        }
    }
    __syncthreads();

    constexpr int LPF = D / 2;
    const int f2   = (t & (LPF - 1)) * 2;
    const int win  = t / LPF;
    const int base = win * 16;

    unsigned hv[16], pv[16];
#pragma unroll
    for (int i = 0; i < 16; i++) {
        unsigned off = (unsigned)src_s[base + i] * D + f2;   // 32-bit offset
        hv[i] = *(const unsigned*)(hbf + off);
        pv[i] = *(const unsigned*)(&msg[(base + i) * LDF + f2]);
    }

    float a0 = 0.f, a1 = 0.f;
    int  cur = dst_x[base + 1];
    bool rs  = (dst_x[base] != cur);

#pragma unroll
    for (int i = 0; i < 16; ++i) {
        int d = dst_x[base + i + 1];
        if (d != cur) {
            if (cur >= 0) {
                unsigned short* ap = agg + ((unsigned)cur * D + f2);
                unsigned v32 = pk(a0, a1);
                if (rs) {
                    *(unsigned*)ap = v32;
                } else {
                    asm volatile("global_atomic_pk_add_bf16 %0, %1, off"
                                 :: "v"(ap), "v"(v32) : "memory");
                }
            }
            a0 = 0.f; a1 = 0.f; rs = true; cur = d;
        }
        a0 += fmaxf(bflo(hv[i]) + bflo(pv[i]), 0.f);
        a1 += fmaxf(bfhi(hv[i]) + bfhi(pv[i]), 0.f);
    }
    if (cur >= 0) {
        bool re = (dst_x[base + 17] != cur);
        unsigned short* ap = agg + ((unsigned)cur * D + f2);
        unsigned v32 = pk(a0, a1);
        if (rs && re) {
            *(unsigned*)ap = v32;
        } else {
            asm volatile("global_atomic_pk_add_bf16 %0, %1, off"
                         :: "v"(ap), "v"(v32) : "memory");
        }
    }
}

// ---------------- fused node MLP v3 (+ optional agg-zero, optional pool)
template<int KIN, bool ZERO, bool POOL>
__global__ __launch_bounds__(THREADS) void fused_mlp_kernel(
    const unsigned short* __restrict__ hin,   // [nrows, KIN] bf16
    const unsigned short* __restrict__ agg,   // [nrows, KIN] bf16
    const unsigned short* __restrict__ Wt1,   // [256, KIN] bf16
    const float* __restrict__ b1,             // [256]
    const unsigned short* __restrict__ Wt2,   // [256, 256] bf16
    const float* __restrict__ b2,             // [256]
    const float* __restrict__ epsp,           // [1]
    unsigned short* __restrict__ out,         // [nrows, 256] bf16 (!POOL)
    uint4* __restrict__ aggz,                 // agg as uint4 (zero target)
    const int* __restrict__ batch,            // [nrows] (POOL)
    float* __restrict__ hg,                   // [G, 256] f32 (POOL)
    int nrows)
{
    constexpr int LDT = 264;                  // 256 + 8 shorts
    __shared__ short Buf[64 * LDT];           // A panel -> Tmp -> pool buffer
    __shared__ int bat[64];

    const int t    = threadIdx.x;
    const int lane = t & 63;
    const int wid  = t >> 6;                  // wave col-stripe
    const int l15  = lane & 15, lgr = lane >> 4;
    const int r0   = blockIdx.x * 64;

    const float scale = 1.0f + epsp[0];

    constexpr int RU = KIN / 8;               // uint4 per row
#pragma unroll
    for (int c = 0; c < (64 * RU) / THREADS; c++) {
        int idx = t + c * THREADS;
        int r   = idx / RU;
        int kq  = idx % RU;
        int row = r0 + r;
        uint4 o = make_uint4(0, 0, 0, 0);
        if (row < nrows) {
            size_t g = (size_t)row * KIN + kq * 8;
            uint4 hv = *(const uint4*)(hin + g);
            uint4 av = *(const uint4*)(agg + g);
            o.x = pk(scale * bflo(hv.x) + bflo(av.x),
                     scale * bfhi(hv.x) + bfhi(av.x));
            o.y = pk(scale * bflo(hv.y) + bflo(av.y),
                     scale * bfhi(hv.y) + bfhi(av.y));
            o.z = pk(scale * bflo(hv.z) + bflo(av.z),
                     scale * bfhi(hv.z) + bfhi(av.z));
            o.w = pk(scale * bflo(hv.w) + bflo(av.w),
                     scale * bfhi(hv.w) + bfhi(av.w));
        }
        *(uint4*)(&Buf[r * LDT + kq * 8]) = o;
    }
    if (POOL && t < 64) {
        int row = r0 + t;
        bat[t] = (row < nrows) ? batch[row] : -1;
    }
    __syncthreads();

    if (ZERO) {
        const unsigned aggTot8 = (unsigned)nrows * 32;   // uint4 units
        const uint4 zz = make_uint4(0, 0, 0, 0);
        if (KIN == 256) {
            unsigned b8 = (unsigned)blockIdx.x * 2048;
#pragma unroll
            for (int c = 0; c < 8; c++) {
                unsigned idx = b8 + t + c * THREADS;
                if (idx < aggTot8) aggz[idx] = zz;
            }
        } else {
            unsigned own  = (unsigned)blockIdx.x * 1024;
            unsigned tail = ((unsigned)gridDim.x + (unsigned)blockIdx.x) * 1024;
#pragma unroll
            for (int c = 0; c < 4; c++) {
                unsigned i1 = own + t + c * THREADS;
                if (i1 < aggTot8) aggz[i1] = zz;
                unsigned i2 = tail + t + c * THREADS;
                if (i2 < aggTot8) aggz[i2] = zz;
            }
        }
    }

    // ---- GEMM1: A from Buf (barrier-free), B direct from global
    f32x4 acc[4][4];
#pragma unroll
    for (int nf = 0; nf < 4; nf++) {
        float bv = b1[wid * 64 + nf * 16 + l15];
#pragma unroll
        for (int mf = 0; mf < 4; mf++)
            acc[mf][nf] = (f32x4){bv, bv, bv, bv};
    }

#pragma unroll
    for (int k0 = 0; k0 < KIN; k0 += 64) {
#pragma unroll
        for (int ks = 0; ks < 2; ks++) {
            bf16x8 afr[4], bfr[4];
#pragma unroll
            for (int nf = 0; nf < 4; nf++)
                bfr[nf] = *(const bf16x8*)(Wt1 +
                    (size_t)(wid * 64 + nf * 16 + l15) * KIN + k0 + ks * 32 + lgr * 8);
#pragma unroll
            for (int mf = 0; mf < 4; mf++)
                afr[mf] = *(const bf16x8*)(&Buf[(mf * 16 + l15) * LDT + k0 + ks * 32 + lgr * 8]);
#pragma unroll
            for (int mf = 0; mf < 4; mf++)
#pragma unroll
                for (int nf = 0; nf < 4; nf++)
                    acc[mf][nf] = __builtin_amdgcn_mfma_f32_16x16x32_bf16(
                        afr[mf], bfr[nf], acc[mf][nf], 0, 0, 0);
        }
    }
    __syncthreads();   // all waves done reading the A panel

    // ---- relu + write z (Tmp) into Buf, re-init acc with b2
#pragma unroll
    for (int nf = 0; nf < 4; nf++) {
        int col = wid * 64 + nf * 16 + l15;
#pragma unroll
        for (int mf = 0; mf < 4; mf++) {
            f32x4 v = acc[mf][nf];
#pragma unroll
            for (int r = 0; r < 4; r++) {
                int row = mf * 16 + lgr * 4 + r;
                Buf[row * LDT + col] = (short)f2bf(fmaxf(v[r], 0.f));
            }
        }
    }
#pragma unroll
    for (int nf = 0; nf < 4; nf++) {
        float bv = b2[wid * 64 + nf * 16 + l15];
#pragma unroll
        for (int mf = 0; mf < 4; mf++)
            acc[mf][nf] = (f32x4){bv, bv, bv, bv};
    }
    __syncthreads();

    // ---- GEMM2: A = Buf (z), B = Wt2 direct from global; barrier-free
#pragma unroll
    for (int k0 = 0; k0 < 256; k0 += 64) {
#pragma unroll
        for (int ks = 0; ks < 2; ks++) {
            bf16x8 afr[4], bfr[4];
#pragma unroll
            for (int nf = 0; nf < 4; nf++)
                bfr[nf] = *(const bf16x8*)(Wt2 +
                    (size_t)(wid * 64 + nf * 16 + l15) * 256 + k0 + ks * 32 + lgr * 8);
#pragma unroll
            for (int mf = 0; mf < 4; mf++)
                afr[mf] = *(const bf16x8*)(&Buf[(mf * 16 + l15) * LDT + k0 + ks * 32 + lgr * 8]);
#pragma unroll
            for (int mf = 0; mf < 4; mf++)
#pragma unroll
                for (int nf = 0; nf < 4; nf++)
                    acc[mf][nf] = __builtin_amdgcn_mfma_f32_16x16x32_bf16(
                        afr[mf], bfr[nf], acc[mf][nf], 0, 0, 0);
        }
    }

    if (!POOL) {
#pragma unroll
        for (int nf = 0; nf < 4; nf++) {
            int col = wid * 64 + nf * 16 + l15;
#pragma unroll
            for (int mf = 0; mf < 4; mf++) {
                f32x4 v = acc[mf][nf];
#pragma unroll
                for (int r = 0; r < 4; r++) {
                    int row = r0 + mf * 16 + lgr * 4 + r;
                    if (row < nrows)
                        out[(size_t)row * 256 + col] = f2bf(fmaxf(v[r], 0.f));
                }
            }
        }
    } else {
        __syncthreads();   // all waves done reading z from Buf
#pragma unroll
        for (int nf = 0; nf < 4; nf++) {
            int col = wid * 64 + nf * 16 + l15;
#pragma unroll
            for (int mf = 0; mf < 4; mf++) {
                f32x4 v = acc[mf][nf];
#pragma unroll
                for (int r = 0; r < 4; r++) {
                    int row = mf * 16 + lgr * 4 + r;
                    Buf[row * LDT + col] = (short)f2bf(fmaxf(v[r], 0.f));
                }
            }
        }
        __syncthreads();

        float a = 0.f;
        int cur = bat[0];
        for (int r = 0; r < 64; ++r) {
            int b = bat[r];
            if (b != cur) {
                if (cur >= 0) atomicAdd(&hg[(size_t)cur * 256 + t], a);
                a = 0.f; cur = b;
            }
            a += bf2f((unsigned short)Buf[r * LDT + t]);
        }
        if (cur >= 0) atomicAdd(&hg[(size_t)cur * 256 + t], a);
    }
}

// ---------------- head
__global__ __launch_bounds__(THREADS) void head_kernel(
    const float* __restrict__ hg,
    const float* __restrict__ w1,
    const float* __restrict__ h1_bmu, const float* __restrict__ h1_bls,
    const float* __restrict__ eps_b1,
    const float* __restrict__ h2_wmu, const float* __restrict__ h2_wls,
    const float* __restrict__ eps_w2,
    const float* __restrict__ h2_bmu, const float* __restrict__ h2_bls,
    const float* __restrict__ eps_b2,
    float* __restrict__ out)
{
    __shared__ float x_s[256];
    __shared__ float red[256];
    const int t = threadIdx.x;
    const int g = blockIdx.x;

    x_s[t] = hg[(size_t)g * 256 + t];
    __syncthreads();

    float acc = h1_bmu[t] + expf(h1_bls[t]) * eps_b1[t];
    for (int kk = 0; kk < 256; kk++) acc += x_s[kk] * w1[kk * 256 + t];
    float h1v = acc / (1.f + expf(-acc));

    float w2a = h2_wmu[t * 2 + 0] + expf(h2_wls[t * 2 + 0]) * eps_w2[t * 2 + 0];
    float w2b = h2_wmu[t * 2 + 1] + expf(h2_wls[t * 2 + 1]) * eps_w2[t * 2 + 1];

    red[t] = h1v * w2a;
    __syncthreads();
    for (int s = 128; s > 0; s >>= 1) {
        if (t < s) red[t] += red[t + s];
        __syncthreads();
    }
    if (t == 0) out[(size_t)g * 2 + 0] = red[0] + h2_bmu[0] + expf(h2_bls[0]) * eps_b2[0];
    __syncthreads();

    red[t] = h1v * w2b;
    __syncthreads();
    for (int s = 128; s > 0; s >>= 1) {
        if (t < s) red[t] += red[t + s];
        __syncthreads();
    }
    if (t == 0) out[(size_t)g * 2 + 1] = red[0] + h2_bmu[1] + expf(h2_bls[1]) * eps_b2[1];
}

// ---------------------------------------------------------------------------
extern "C" void kernel_launch(void* const* d_in, const int* in_sizes, int n_in,
                              void* d_out, int out_size, void* d_ws, size_t ws_size,
                              hipStream_t stream)
{
    const float* x         = (const float*)d_in[0];
    const float* edge_attr = (const float*)d_in[1];
    const int*   ei        = (const int*)d_in[2];
    const int*   batch     = (const int*)d_in[3];

    const float* We[3]  = { (const float*)d_in[4],  (const float*)d_in[11], (const float*)d_in[18] };
    const float* be[3]  = { (const float*)d_in[5],  (const float*)d_in[12], (const float*)d_in[19] };
    const float* W1[3]  = { (const float*)d_in[6],  (const float*)d_in[13], (const float*)d_in[20] };
    const float* b1[3]  = { (const float*)d_in[7],  (const float*)d_in[14], (const float*)d_in[21] };
    const float* W2[3]  = { (const float*)d_in[8],  (const float*)d_in[15], (const float*)d_in[22] };
    const float* b2[3]  = { (const float*)d_in[9],  (const float*)d_in[16], (const float*)d_in[23] };
    const float* epsl[3]= { (const float*)d_in[10], (const float*)d_in[17], (const float*)d_in[24] };

    const float* h1_wmu = (const float*)d_in[25];
    const float* h1_wls = (const float*)d_in[26];
    const float* h1_bmu = (const float*)d_in[27];
    const float* h1_bls = (const float*)d_in[28];
    const float* h2_wmu = (const float*)d_in[29];
    const float* h2_wls = (const float*)d_in[30];
    const float* h2_bmu = (const float*)d_in[31];
    const float* h2_bls = (const float*)d_in[32];
    const float* eps_w1 = (const float*)d_in[33];
    const float* eps_b1 = (const float*)d_in[34];
    const float* eps_w2 = (const float*)d_in[35];
    const float* eps_b2 = (const float*)d_in[36];

    const int N = in_sizes[0] / 128;
    const int E = in_sizes[1] / 16;
    const int G = out_size / 2;

    // ---- carve workspace (256B aligned chunks)
    uintptr_t p = (uintptr_t)d_ws;
    auto carve = [&](size_t bytes) -> void* {
        void* r = (void*)p;
        p = (p + bytes + 255) & ~(uintptr_t)255;
        return r;
    };
    float* hg      = (float*)carve((size_t)G * 256 * 4);
    float* w1buf   = (float*)carve(256 * 256 * 4);
    int*   rowptr  = (int*)carve((size_t)(N + 1) * 4);
    int*   cursor  = (int*)carve((size_t)(N + 4) * 4);   // +pad for uint4 zeroing
    int*   csr_src = (int*)carve((size_t)E * 4);
    int*   csr_dst = (int*)carve((size_t)E * 4);
    unsigned short* aggbf = (unsigned short*)carve(((size_t)N * 256 + 16384) * 2);
    unsigned short* ea16  = (unsigned short*)carve((size_t)E * 16 * 2);
    unsigned short* hbf   = (unsigned short*)carve((size_t)N * 256 * 2);
    unsigned short* xbf   = (unsigned short*)carve((size_t)N * 128 * 2);
    unsigned short* wep[3];
    wep[0] = (unsigned short*)carve(128 * 32 * 2);
    wep[1] = (unsigned short*)carve(256 * 32 * 2);
    wep[2] = (unsigned short*)carve(256 * 32 * 2);
    unsigned short* wt1[3], *wt2[3];
    wt1[0] = (unsigned short*)carve(256 * 128 * 2);
    for (int l = 0; l < 3; l++) {
        if (l) wt1[l] = (unsigned short*)carve(256 * 256 * 2);
        wt2[l] = (unsigned short*)carve(256 * 256 * 2);
    }

    const int eblocks    = (E + THREADS - 1) / THREADS;
    const int mlp_blocks = (N + 63) / 64;

    float* out = (float*)d_out;

    // ---- xprep first: converts x, zeroes aggbf + hg + cursor (no memset)
    xprep_kernel<<<(N * 32 + THREADS - 1) / THREADS, THREADS, 0, stream>>>(
        x, xbf, N * 32, (uint4*)aggbf, N * 32, (float4*)hg, G * 64,
        (uint4*)cursor, (N + 3) / 4);

    // ---- CSR build: hist -> scan (zeroes cursor) -> fill
    hist_kernel<<<eblocks, THREADS, 0, stream>>>(ei, cursor, E);
    scan_kernel<<<1, 1024, 0, stream>>>(cursor, rowptr, N);
    fill_kernel<<<eblocks, THREADS, 0, stream>>>(
        ei, rowptr, cursor, csr_src, csr_dst, edge_attr, ea16, E);

    // ---- unified weight prep (1 dispatch)
    PrepArgs pa;
    pa.W[0] = W1[0]; pa.Wt[0] = wt1[0]; pa.K[0] = 128;
    pa.W[1] = W2[0]; pa.Wt[1] = wt2[0]; pa.K[1] = 256;
    pa.W[2] = W1[1]; pa.Wt[2] = wt1[1]; pa.K[2] = 256;
    pa.W[3] = W2[1]; pa.Wt[3] = wt2[1]; pa.K[3] = 256;
    pa.W[4] = W1[2]; pa.Wt[4] = wt1[2]; pa.K[4] = 256;
    pa.W[5] = W2[2]; pa.Wt[5] = wt2[2]; pa.K[5] = 256;
    pa.mu = h1_wmu; pa.ls = h1_wls; pa.eps = eps_w1; pa.w1buf = w1buf;
    for (int l = 0; l < 3; l++) { pa.We[l] = We[l]; pa.Wp[l] = wep[l]; }
    pa.D[0] = 128; pa.D[1] = 256; pa.D[2] = 256;
    prep_kernel<<<dim3(8, 8, 8), THREADS, 0, stream>>>(pa);

    // ---- layer 0 (d = 128, h = xbf)
    edge_agg_kernel<128><<<(E + 63) / 64, THREADS, 0, stream>>>(
        xbf, ea16, csr_src, csr_dst, wep[0], be[0], aggbf, E);
    fused_mlp_kernel<128, true, false><<<mlp_blocks, THREADS, 0, stream>>>(
        xbf, aggbf, wt1[0], b1[0], wt2[0], b2[0], epsl[0], hbf, (uint4*)aggbf,
        nullptr, nullptr, N);

    // ---- layer 1 (d = 256)
    edge_agg_kernel<256><<<(E + 31) / 32, THREADS, 0, stream>>>(
        hbf, ea16, csr_src, csr_dst, wep[1], be[1], aggbf, E);
    fused_mlp_kernel<256, true, false><<<mlp_blocks, THREADS, 0, stream>>>(
        hbf, aggbf, wt1[1], b1[1], wt2[1], b2[1], epsl[1], hbf, (uint4*)aggbf,
        nullptr, nullptr, N);

    // ---- layer 2 (d = 256): fused pool into hg, no hbf write
    edge_agg_kernel<256><<<(E + 31) / 32, THREADS, 0, stream>>>(
        hbf, ea16, csr_src, csr_dst, wep[2], be[2], aggbf, E);
    fused_mlp_kernel<256, false, true><<<mlp_blocks, THREADS, 0, stream>>>(
        hbf, aggbf, wt1[2], b1[2], wt2[2], b2[2], epsl[2], hbf, (uint4*)aggbf,
        batch, hg, N);

    // ---- Bayesian head (w1buf from prep_kernel)
    head_kernel<<<G, THREADS, 0, stream>>>(
        hg, w1buf, h1_bmu, h1_bls, eps_b1,
        h2_wmu, h2_wls, eps_w2, h2_bmu, h2_bls, eps_b2, out);
}

// Round 18
// 391.454 us; speedup vs baseline: 1.2053x; 1.2053x over previous
//
#include <hip/hip_runtime.h>
#include <hip/hip_bf16.h>
#include <math.h>

// ---------------------------------------------------------------------------
// GINE x3 + global_add_pool + Bayesian head.
// Round 18: R17's scan regression reverted (back to R16's coalesced int4
// chunked scan, in-pass cursor zeroing). Kept: memset folded into xprep,
// xprep first. Compute kernels identical to R16.
// ---------------------------------------------------------------------------

#define THREADS 256

typedef __attribute__((ext_vector_type(8))) short bf16x8;
typedef __attribute__((ext_vector_type(4))) float f32x4;

__device__ __forceinline__ unsigned short f2bf(float x) {
    __hip_bfloat16 h = __float2bfloat16(x);
    return __builtin_bit_cast(unsigned short, h);
}
__device__ __forceinline__ float bflo(unsigned u) {
    return __builtin_bit_cast(float, u << 16);
}
__device__ __forceinline__ float bfhi(unsigned u) {
    return __builtin_bit_cast(float, u & 0xffff0000u);
}
__device__ __forceinline__ float bf2f(unsigned short u) {
    return __builtin_bit_cast(float, (unsigned)u << 16);
}
__device__ __forceinline__ unsigned pk(float a, float b) {
    return (unsigned)f2bf(a) | ((unsigned)f2bf(b) << 16);
}

// ---------------- CSR build: histogram of dst
__global__ __launch_bounds__(THREADS) void hist_kernel(
    const int* __restrict__ ei, int* __restrict__ deg, int E)
{
    int e = blockIdx.x * THREADS + threadIdx.x;
    if (e < E) atomicAdd(&deg[ei[E + e]], 1);
}

// ---------------- CSR build: int4 + wave-shuffle exclusive scan (coalesced).
// Also zeroes deg (=cursor) in-pass for the subsequent fill_kernel.
__global__ __launch_bounds__(1024) void scan_kernel(
    int* __restrict__ deg, int* __restrict__ rowptr, int n)
{
    __shared__ int wsum[16];
    __shared__ int carry_s;
    const int t    = threadIdx.x;
    const int lane = t & 63, wv = t >> 6;
    if (t == 0) carry_s = 0;
    __syncthreads();
    for (int base = 0; base < n; base += 4096) {
        int i = base + t * 4;
        int4 v = make_int4(0, 0, 0, 0);
        if (i + 3 < n) {
            v = *(const int4*)(deg + i);
            *(int4*)(deg + i) = make_int4(0, 0, 0, 0);
        } else if (i < n) {
            v.x = deg[i];                    deg[i] = 0;
            if (i + 1 < n) { v.y = deg[i+1]; deg[i+1] = 0; }
            if (i + 2 < n) { v.z = deg[i+2]; deg[i+2] = 0; }
        }
        int p1 = v.x + v.y, p2 = p1 + v.z, tot = p2 + v.w;
        int incl = tot;
#pragma unroll
        for (int off = 1; off < 64; off <<= 1) {
            int u = __shfl_up(incl, off, 64);
            if (lane >= off) incl += u;
        }
        if (lane == 63) wsum[wv] = incl;
        __syncthreads();
        if (wv == 0) {
            int s = (lane < 16) ? wsum[lane] : 0;
#pragma unroll
            for (int off = 1; off < 16; off <<= 1) {
                int u = __shfl_up(s, off, 64);
                if (lane >= off) s += u;
            }
            if (lane < 16) wsum[lane] = s;
        }
        __syncthreads();
        int waveoff = (wv == 0) ? 0 : wsum[wv - 1];
        int tbase   = carry_s + waveoff + incl - tot;   // exclusive base
        if (i     < n) rowptr[i + 1] = tbase + v.x;
        if (i + 1 < n) rowptr[i + 2] = tbase + p1;
        if (i + 2 < n) rowptr[i + 3] = tbase + p2;
        if (i + 3 < n) rowptr[i + 4] = tbase + tot;
        __syncthreads();
        if (t == 1023) carry_s = carry_s + wsum[15];
        __syncthreads();
    }
    if (t == 0) rowptr[0] = 0;
}

// ---------------- CSR build: scatter edges into slots + ea16 (fused easort)
__global__ __launch_bounds__(THREADS) void fill_kernel(
    const int* __restrict__ ei, const int* __restrict__ rowptr,
    int* __restrict__ cursor, int* __restrict__ csr_src,
    int* __restrict__ csr_dst, const float* __restrict__ edge_attr,
    unsigned short* __restrict__ ea16, int E)
{
    int e = blockIdx.x * THREADS + threadIdx.x;
    if (e >= E) return;
    int s = ei[e], d = ei[E + e];
    int pos  = atomicAdd(&cursor[d], 1);
    int slot = rowptr[d] + pos;
    csr_src[slot] = s;
    csr_dst[slot] = d;
    const float4* a = (const float4*)(edge_attr + (size_t)e * 16);
    float4 a0 = a[0], a1 = a[1], a2 = a[2], a3 = a[3];
    uint4* dst = (uint4*)(ea16 + (size_t)slot * 16);
    dst[0] = make_uint4(pk(a0.x, a0.y), pk(a0.z, a0.w), pk(a1.x, a1.y), pk(a1.z, a1.w));
    dst[1] = make_uint4(pk(a2.x, a2.y), pk(a2.z, a2.w), pk(a3.x, a3.y), pk(a3.z, a3.w));
}

// ---------------- x -> bf16 copy; zeroes aggbf, hg, AND cursor
__global__ __launch_bounds__(THREADS) void xprep_kernel(
    const float* __restrict__ x, unsigned short* __restrict__ xbf, int n4,
    uint4* __restrict__ aggz, int nAgg4,
    float4* __restrict__ hgz, int nHg4,
    uint4* __restrict__ curz, int nCur4)
{
    int i = blockIdx.x * THREADS + threadIdx.x;
    if (i < n4) {
        float4 v = ((const float4*)x)[i];
        uint2 p;
        p.x = pk(v.x, v.y);
        p.y = pk(v.z, v.w);
        ((uint2*)xbf)[i] = p;
    }
    if (i < nAgg4) aggz[i] = make_uint4(0, 0, 0, 0);
    if (i < nHg4)  hgz[i]  = make_float4(0.f, 0.f, 0.f, 0.f);
    if (i < nCur4) curz[i] = make_uint4(0, 0, 0, 0);
}

// ---------------- unified weight prep
struct PrepArgs {
    const float* W[6]; unsigned short* Wt[6]; int K[6];
    const float* mu; const float* ls; const float* eps; float* w1buf;
    const float* We[3]; unsigned short* Wp[3]; int D[3];
};
__global__ __launch_bounds__(THREADS) void prep_kernel(PrepArgs a)
{
    __shared__ float tile[32][33];
    const int z = blockIdx.z;
    const int t = threadIdx.x;

    if (z < 6) {
        const int K = a.K[z];
        const int kb = blockIdx.x * 32;
        if (kb >= K) return;
        const float* W = a.W[z];
        unsigned short* Wt = a.Wt[z];
        const int nb = blockIdx.y * 32;
        const int tx = t & 31, ty = t >> 5;
#pragma unroll
        for (int i = ty; i < 32; i += 8)
            tile[i][tx] = W[(size_t)(kb + i) * 256 + nb + tx];
        __syncthreads();
#pragma unroll
        for (int i = ty; i < 32; i += 8)
            Wt[(size_t)(nb + i) * K + kb + tx] = f2bf(tile[tx][i]);
    } else if (z == 6) {
        int blk = blockIdx.x + blockIdx.y * 8;         // 0..63
#pragma unroll
        for (int c = 0; c < 4; c++) {
            int i = blk * THREADS + t + c * 16384;     // covers 65536
            a.w1buf[i] = a.mu[i] + expf(a.ls[i]) * a.eps[i];
        }
    } else {
        int l = blockIdx.x + blockIdx.y * 8;
        if (l >= 3) return;
        int D = a.D[l];
        if (t >= D) return;
        const float* We = a.We[l];
        unsigned short* Wp = a.Wp[l];
#pragma unroll
        for (int k = 0; k < 16; k++) Wp[t * 32 + k] = f2bf(We[k * D + t]);
#pragma unroll
        for (int k = 16; k < 32; k++) Wp[t * 32 + k] = 0;
    }
}

// ---------------- fused MFMA aggregation (2 feats/lane config)
template<int D>
__global__ __launch_bounds__(THREADS) void edge_agg_kernel(
    const unsigned short* __restrict__ hbf,   // [N][D] bf16
    const unsigned short* __restrict__ ea16,  // [E][16] bf16, CSR order
    const int* __restrict__ csr_src,          // [E]
    const int* __restrict__ csr_dst,          // [E] (non-decreasing)
    const unsigned short* __restrict__ Wtp,   // [D][32] bf16, k>=16 zero
    const float* __restrict__ be,             // [D]
    unsigned short* __restrict__ agg,         // [N][D] bf16, pre-zeroed
    int E)
{
    constexpr int EPB = (D == 128) ? 64 : 32;    // edges per block
    constexpr int LDF = D + 8;                   // padded LDS stride (shorts)
    __shared__ unsigned short msg[EPB * LDF];
    __shared__ int src_s[EPB];
    __shared__ int dst_x[EPB + 2];               // dst of edges e0-1 .. e0+EPB

    const int t    = threadIdx.x;
    const int e0   = blockIdx.x * EPB;
    const int lane = t & 63, wid = t >> 6;
    const int l15  = lane & 15, lgr = lane >> 4;

    for (int i = t; i < EPB; i += THREADS) {
        int e = e0 + i;
        src_s[i] = (e < E) ? csr_src[e] : 0;
    }
    for (int i = t; i < EPB + 2; i += THREADS) {
        int e = e0 + i - 1;
        dst_x[i] = (e < 0) ? -2 : ((e < E) ? csr_dst[e] : -1);
    }

    const int fb = (D == 128) ? (wid & 1) * 64 : wid * 64;   // feature base
    const int eb = (D == 128) ? (wid >> 1) * 32 : 0;         // edge base

    bf16x8 af[4];
#pragma unroll
    for (int mf = 0; mf < 4; mf++)
        af[mf] = *(const bf16x8*)(Wtp + (unsigned)(fb + mf * 16 + l15) * 32 + lgr * 8);

    f32x4 acc[4][2];
#pragma unroll
    for (int mf = 0; mf < 4; mf++) {
        int fpos = fb + mf * 16 + lgr * 4;
        float4 bv4 = *(const float4*)(be + fpos);
        f32x4 binit = (f32x4){bv4.x, bv4.y, bv4.z, bv4.w};
        acc[mf][0] = binit;
        acc[mf][1] = binit;
    }

#pragma unroll
    for (int nf = 0; nf < 2; nf++) {
        int er = e0 + eb + nf * 16 + l15;
        bf16x8 bv = (bf16x8){0, 0, 0, 0, 0, 0, 0, 0};
        if (lgr < 2 && er < E)
            bv = *(const bf16x8*)(ea16 + (size_t)er * 16 + lgr * 8);
#pragma unroll
        for (int mf = 0; mf < 4; mf++)
            acc[mf][nf] = __builtin_amdgcn_mfma_f32_16x16x32_bf16(
                af[mf], bv, acc[mf][nf], 0, 0, 0);
    }

#pragma unroll
    for (int nf = 0; nf < 2; nf++) {
        int edge = eb + nf * 16 + l15;
#pragma unroll
        for (int mf = 0; mf < 4; mf++) {
            int fpos = fb + mf * 16 + lgr * 4;
            f32x4 v = acc[mf][nf];
            uint2 p;
            p.x = pk(v[0], v[1]);
            p.y = pk(v[2], v[3]);
            *(uint2*)(&msg[edge * LDF + fpos]) = p;
        }
    }
    __syncthreads();

    constexpr int LPF = D / 2;
    const int f2   = (t & (LPF - 1)) * 2;
    const int win  = t / LPF;
    const int base = win * 16;

    unsigned hv[16], pv[16];
#pragma unroll
    for (int i = 0; i < 16; i++) {
        unsigned off = (unsigned)src_s[base + i] * D + f2;   // 32-bit offset
        hv[i] = *(const unsigned*)(hbf + off);
        pv[i] = *(const unsigned*)(&msg[(base + i) * LDF + f2]);
    }

    float a0 = 0.f, a1 = 0.f;
    int  cur = dst_x[base + 1];
    bool rs  = (dst_x[base] != cur);

#pragma unroll
    for (int i = 0; i < 16; ++i) {
        int d = dst_x[base + i + 1];
        if (d != cur) {
            if (cur >= 0) {
                unsigned short* ap = agg + ((unsigned)cur * D + f2);
                unsigned v32 = pk(a0, a1);
                if (rs) {
                    *(unsigned*)ap = v32;
                } else {
                    asm volatile("global_atomic_pk_add_bf16 %0, %1, off"
                                 :: "v"(ap), "v"(v32) : "memory");
                }
            }
            a0 = 0.f; a1 = 0.f; rs = true; cur = d;
        }
        a0 += fmaxf(bflo(hv[i]) + bflo(pv[i]), 0.f);
        a1 += fmaxf(bfhi(hv[i]) + bfhi(pv[i]), 0.f);
    }
    if (cur >= 0) {
        bool re = (dst_x[base + 17] != cur);
        unsigned short* ap = agg + ((unsigned)cur * D + f2);
        unsigned v32 = pk(a0, a1);
        if (rs && re) {
            *(unsigned*)ap = v32;
        } else {
            asm volatile("global_atomic_pk_add_bf16 %0, %1, off"
                         :: "v"(ap), "v"(v32) : "memory");
        }
    }
}

// ---------------- fused node MLP v3 (+ optional agg-zero, optional pool)
template<int KIN, bool ZERO, bool POOL>
__global__ __launch_bounds__(THREADS) void fused_mlp_kernel(
    const unsigned short* __restrict__ hin,   // [nrows, KIN] bf16
    const unsigned short* __restrict__ agg,   // [nrows, KIN] bf16
    const unsigned short* __restrict__ Wt1,   // [256, KIN] bf16
    const float* __restrict__ b1,             // [256]
    const unsigned short* __restrict__ Wt2,   // [256, 256] bf16
    const float* __restrict__ b2,             // [256]
    const float* __restrict__ epsp,           // [1]
    unsigned short* __restrict__ out,         // [nrows, 256] bf16 (!POOL)
    uint4* __restrict__ aggz,                 // agg as uint4 (zero target)
    const int* __restrict__ batch,            // [nrows] (POOL)
    float* __restrict__ hg,                   // [G, 256] f32 (POOL)
    int nrows)
{
    constexpr int LDT = 264;                  // 256 + 8 shorts
    __shared__ short Buf[64 * LDT];           // A panel -> Tmp -> pool buffer
    __shared__ int bat[64];

    const int t    = threadIdx.x;
    const int lane = t & 63;
    const int wid  = t >> 6;                  // wave col-stripe
    const int l15  = lane & 15, lgr = lane >> 4;
    const int r0   = blockIdx.x * 64;

    const float scale = 1.0f + epsp[0];

    constexpr int RU = KIN / 8;               // uint4 per row
#pragma unroll
    for (int c = 0; c < (64 * RU) / THREADS; c++) {
        int idx = t + c * THREADS;
        int r   = idx / RU;
        int kq  = idx % RU;
        int row = r0 + r;
        uint4 o = make_uint4(0, 0, 0, 0);
        if (row < nrows) {
            size_t g = (size_t)row * KIN + kq * 8;
            uint4 hv = *(const uint4*)(hin + g);
            uint4 av = *(const uint4*)(agg + g);
            o.x = pk(scale * bflo(hv.x) + bflo(av.x),
                     scale * bfhi(hv.x) + bfhi(av.x));
            o.y = pk(scale * bflo(hv.y) + bflo(av.y),
                     scale * bfhi(hv.y) + bfhi(av.y));
            o.z = pk(scale * bflo(hv.z) + bflo(av.z),
                     scale * bfhi(hv.z) + bfhi(av.z));
            o.w = pk(scale * bflo(hv.w) + bflo(av.w),
                     scale * bfhi(hv.w) + bfhi(av.w));
        }
        *(uint4*)(&Buf[r * LDT + kq * 8]) = o;
    }
    if (POOL && t < 64) {
        int row = r0 + t;
        bat[t] = (row < nrows) ? batch[row] : -1;
    }
    __syncthreads();

    if (ZERO) {
        const unsigned aggTot8 = (unsigned)nrows * 32;   // uint4 units
        const uint4 zz = make_uint4(0, 0, 0, 0);
        if (KIN == 256) {
            unsigned b8 = (unsigned)blockIdx.x * 2048;
#pragma unroll
            for (int c = 0; c < 8; c++) {
                unsigned idx = b8 + t + c * THREADS;
                if (idx < aggTot8) aggz[idx] = zz;
            }
        } else {
            unsigned own  = (unsigned)blockIdx.x * 1024;
            unsigned tail = ((unsigned)gridDim.x + (unsigned)blockIdx.x) * 1024;
#pragma unroll
            for (int c = 0; c < 4; c++) {
                unsigned i1 = own + t + c * THREADS;
                if (i1 < aggTot8) aggz[i1] = zz;
                unsigned i2 = tail + t + c * THREADS;
                if (i2 < aggTot8) aggz[i2] = zz;
            }
        }
    }

    // ---- GEMM1: A from Buf (barrier-free), B direct from global
    f32x4 acc[4][4];
#pragma unroll
    for (int nf = 0; nf < 4; nf++) {
        float bv = b1[wid * 64 + nf * 16 + l15];
#pragma unroll
        for (int mf = 0; mf < 4; mf++)
            acc[mf][nf] = (f32x4){bv, bv, bv, bv};
    }

#pragma unroll
    for (int k0 = 0; k0 < KIN; k0 += 64) {
#pragma unroll
        for (int ks = 0; ks < 2; ks++) {
            bf16x8 afr[4], bfr[4];
#pragma unroll
            for (int nf = 0; nf < 4; nf++)
                bfr[nf] = *(const bf16x8*)(Wt1 +
                    (size_t)(wid * 64 + nf * 16 + l15) * KIN + k0 + ks * 32 + lgr * 8);
#pragma unroll
            for (int mf = 0; mf < 4; mf++)
                afr[mf] = *(const bf16x8*)(&Buf[(mf * 16 + l15) * LDT + k0 + ks * 32 + lgr * 8]);
#pragma unroll
            for (int mf = 0; mf < 4; mf++)
#pragma unroll
                for (int nf = 0; nf < 4; nf++)
                    acc[mf][nf] = __builtin_amdgcn_mfma_f32_16x16x32_bf16(
                        afr[mf], bfr[nf], acc[mf][nf], 0, 0, 0);
        }
    }
    __syncthreads();   // all waves done reading the A panel

    // ---- relu + write z (Tmp) into Buf, re-init acc with b2
#pragma unroll
    for (int nf = 0; nf < 4; nf++) {
        int col = wid * 64 + nf * 16 + l15;
#pragma unroll
        for (int mf = 0; mf < 4; mf++) {
            f32x4 v = acc[mf][nf];
#pragma unroll
            for (int r = 0; r < 4; r++) {
                int row = mf * 16 + lgr * 4 + r;
                Buf[row * LDT + col] = (short)f2bf(fmaxf(v[r], 0.f));
            }
        }
    }
#pragma unroll
    for (int nf = 0; nf < 4; nf++) {
        float bv = b2[wid * 64 + nf * 16 + l15];
#pragma unroll
        for (int mf = 0; mf < 4; mf++)
            acc[mf][nf] = (f32x4){bv, bv, bv, bv};
    }
    __syncthreads();

    // ---- GEMM2: A = Buf (z), B = Wt2 direct from global; barrier-free
#pragma unroll
    for (int k0 = 0; k0 < 256; k0 += 64) {
#pragma unroll
        for (int ks = 0; ks < 2; ks++) {
            bf16x8 afr[4], bfr[4];
#pragma unroll
            for (int nf = 0; nf < 4; nf++)
                bfr[nf] = *(const bf16x8*)(Wt2 +
                    (size_t)(wid * 64 + nf * 16 + l15) * 256 + k0 + ks * 32 + lgr * 8);
#pragma unroll
            for (int mf = 0; mf < 4; mf++)
                afr[mf] = *(const bf16x8*)(&Buf[(mf * 16 + l15) * LDT + k0 + ks * 32 + lgr * 8]);
#pragma unroll
            for (int mf = 0; mf < 4; mf++)
#pragma unroll
                for (int nf = 0; nf < 4; nf++)
                    acc[mf][nf] = __builtin_amdgcn_mfma_f32_16x16x32_bf16(
                        afr[mf], bfr[nf], acc[mf][nf], 0, 0, 0);
        }
    }

    if (!POOL) {
#pragma unroll
        for (int nf = 0; nf < 4; nf++) {
            int col = wid * 64 + nf * 16 + l15;
#pragma unroll
            for (int mf = 0; mf < 4; mf++) {
                f32x4 v = acc[mf][nf];
#pragma unroll
                for (int r = 0; r < 4; r++) {
                    int row = r0 + mf * 16 + lgr * 4 + r;
                    if (row < nrows)
                        out[(size_t)row * 256 + col] = f2bf(fmaxf(v[r], 0.f));
                }
            }
        }
    } else {
        __syncthreads();   // all waves done reading z from Buf
#pragma unroll
        for (int nf = 0; nf < 4; nf++) {
            int col = wid * 64 + nf * 16 + l15;
#pragma unroll
            for (int mf = 0; mf < 4; mf++) {
                f32x4 v = acc[mf][nf];
#pragma unroll
                for (int r = 0; r < 4; r++) {
                    int row = mf * 16 + lgr * 4 + r;
                    Buf[row * LDT + col] = (short)f2bf(fmaxf(v[r], 0.f));
                }
            }
        }
        __syncthreads();

        float a = 0.f;
        int cur = bat[0];
        for (int r = 0; r < 64; ++r) {
            int b = bat[r];
            if (b != cur) {
                if (cur >= 0) atomicAdd(&hg[(size_t)cur * 256 + t], a);
                a = 0.f; cur = b;
            }
            a += bf2f((unsigned short)Buf[r * LDT + t]);
        }
        if (cur >= 0) atomicAdd(&hg[(size_t)cur * 256 + t], a);
    }
}

// ---------------- head
__global__ __launch_bounds__(THREADS) void head_kernel(
    const float* __restrict__ hg,
    const float* __restrict__ w1,
    const float* __restrict__ h1_bmu, const float* __restrict__ h1_bls,
    const float* __restrict__ eps_b1,
    const float* __restrict__ h2_wmu, const float* __restrict__ h2_wls,
    const float* __restrict__ eps_w2,
    const float* __restrict__ h2_bmu, const float* __restrict__ h2_bls,
    const float* __restrict__ eps_b2,
    float* __restrict__ out)
{
    __shared__ float x_s[256];
    __shared__ float red[256];
    const int t = threadIdx.x;
    const int g = blockIdx.x;

    x_s[t] = hg[(size_t)g * 256 + t];
    __syncthreads();

    float acc = h1_bmu[t] + expf(h1_bls[t]) * eps_b1[t];
    for (int kk = 0; kk < 256; kk++) acc += x_s[kk] * w1[kk * 256 + t];
    float h1v = acc / (1.f + expf(-acc));

    float w2a = h2_wmu[t * 2 + 0] + expf(h2_wls[t * 2 + 0]) * eps_w2[t * 2 + 0];
    float w2b = h2_wmu[t * 2 + 1] + expf(h2_wls[t * 2 + 1]) * eps_w2[t * 2 + 1];

    red[t] = h1v * w2a;
    __syncthreads();
    for (int s = 128; s > 0; s >>= 1) {
        if (t < s) red[t] += red[t + s];
        __syncthreads();
    }
    if (t == 0) out[(size_t)g * 2 + 0] = red[0] + h2_bmu[0] + expf(h2_bls[0]) * eps_b2[0];
    __syncthreads();

    red[t] = h1v * w2b;
    __syncthreads();
    for (int s = 128; s > 0; s >>= 1) {
        if (t < s) red[t] += red[t + s];
        __syncthreads();
    }
    if (t == 0) out[(size_t)g * 2 + 1] = red[0] + h2_bmu[1] + expf(h2_bls[1]) * eps_b2[1];
}

// ---------------------------------------------------------------------------
extern "C" void kernel_launch(void* const* d_in, const int* in_sizes, int n_in,
                              void* d_out, int out_size, void* d_ws, size_t ws_size,
                              hipStream_t stream)
{
    const float* x         = (const float*)d_in[0];
    const float* edge_attr = (const float*)d_in[1];
    const int*   ei        = (const int*)d_in[2];
    const int*   batch     = (const int*)d_in[3];

    const float* We[3]  = { (const float*)d_in[4],  (const float*)d_in[11], (const float*)d_in[18] };
    const float* be[3]  = { (const float*)d_in[5],  (const float*)d_in[12], (const float*)d_in[19] };
    const float* W1[3]  = { (const float*)d_in[6],  (const float*)d_in[13], (const float*)d_in[20] };
    const float* b1[3]  = { (const float*)d_in[7],  (const float*)d_in[14], (const float*)d_in[21] };
    const float* W2[3]  = { (const float*)d_in[8],  (const float*)d_in[15], (const float*)d_in[22] };
    const float* b2[3]  = { (const float*)d_in[9],  (const float*)d_in[16], (const float*)d_in[23] };
    const float* epsl[3]= { (const float*)d_in[10], (const float*)d_in[17], (const float*)d_in[24] };

    const float* h1_wmu = (const float*)d_in[25];
    const float* h1_wls = (const float*)d_in[26];
    const float* h1_bmu = (const float*)d_in[27];
    const float* h1_bls = (const float*)d_in[28];
    const float* h2_wmu = (const float*)d_in[29];
    const float* h2_wls = (const float*)d_in[30];
    const float* h2_bmu = (const float*)d_in[31];
    const float* h2_bls = (const float*)d_in[32];
    const float* eps_w1 = (const float*)d_in[33];
    const float* eps_b1 = (const float*)d_in[34];
    const float* eps_w2 = (const float*)d_in[35];
    const float* eps_b2 = (const float*)d_in[36];

    const int N = in_sizes[0] / 128;
    const int E = in_sizes[1] / 16;
    const int G = out_size / 2;

    // ---- carve workspace (256B aligned chunks)
    uintptr_t p = (uintptr_t)d_ws;
    auto carve = [&](size_t bytes) -> void* {
        void* r = (void*)p;
        p = (p + bytes + 255) & ~(uintptr_t)255;
        return r;
    };
    float* hg      = (float*)carve((size_t)G * 256 * 4);
    float* w1buf   = (float*)carve(256 * 256 * 4);
    int*   rowptr  = (int*)carve((size_t)(N + 1) * 4);
    int*   cursor  = (int*)carve((size_t)(N + 4) * 4);   // +pad for uint4 zeroing
    int*   csr_src = (int*)carve((size_t)E * 4);
    int*   csr_dst = (int*)carve((size_t)E * 4);
    unsigned short* aggbf = (unsigned short*)carve(((size_t)N * 256 + 16384) * 2);
    unsigned short* ea16  = (unsigned short*)carve((size_t)E * 16 * 2);
    unsigned short* hbf   = (unsigned short*)carve((size_t)N * 256 * 2);
    unsigned short* xbf   = (unsigned short*)carve((size_t)N * 128 * 2);
    unsigned short* wep[3];
    wep[0] = (unsigned short*)carve(128 * 32 * 2);
    wep[1] = (unsigned short*)carve(256 * 32 * 2);
    wep[2] = (unsigned short*)carve(256 * 32 * 2);
    unsigned short* wt1[3], *wt2[3];
    wt1[0] = (unsigned short*)carve(256 * 128 * 2);
    for (int l = 0; l < 3; l++) {
        if (l) wt1[l] = (unsigned short*)carve(256 * 256 * 2);
        wt2[l] = (unsigned short*)carve(256 * 256 * 2);
    }

    const int eblocks    = (E + THREADS - 1) / THREADS;
    const int mlp_blocks = (N + 63) / 64;

    float* out = (float*)d_out;

    // ---- xprep first: converts x, zeroes aggbf + hg + cursor (no memset)
    xprep_kernel<<<(N * 32 + THREADS - 1) / THREADS, THREADS, 0, stream>>>(
        x, xbf, N * 32, (uint4*)aggbf, N * 32, (float4*)hg, G * 64,
        (uint4*)cursor, (N + 3) / 4);

    // ---- CSR build: hist -> scan (zeroes cursor) -> fill
    hist_kernel<<<eblocks, THREADS, 0, stream>>>(ei, cursor, E);
    scan_kernel<<<1, 1024, 0, stream>>>(cursor, rowptr, N);
    fill_kernel<<<eblocks, THREADS, 0, stream>>>(
        ei, rowptr, cursor, csr_src, csr_dst, edge_attr, ea16, E);

    // ---- unified weight prep (1 dispatch)
    PrepArgs pa;
    pa.W[0] = W1[0]; pa.Wt[0] = wt1[0]; pa.K[0] = 128;
    pa.W[1] = W2[0]; pa.Wt[1] = wt2[0]; pa.K[1] = 256;
    pa.W[2] = W1[1]; pa.Wt[2] = wt1[1]; pa.K[2] = 256;
    pa.W[3] = W2[1]; pa.Wt[3] = wt2[1]; pa.K[3] = 256;
    pa.W[4] = W1[2]; pa.Wt[4] = wt1[2]; pa.K[4] = 256;
    pa.W[5] = W2[2]; pa.Wt[5] = wt2[2]; pa.K[5] = 256;
    pa.mu = h1_wmu; pa.ls = h1_wls; pa.eps = eps_w1; pa.w1buf = w1buf;
    for (int l = 0; l < 3; l++) { pa.We[l] = We[l]; pa.Wp[l] = wep[l]; }
    pa.D[0] = 128; pa.D[1] = 256; pa.D[2] = 256;
    prep_kernel<<<dim3(8, 8, 8), THREADS, 0, stream>>>(pa);

    // ---- layer 0 (d = 128, h = xbf)
    edge_agg_kernel<128><<<(E + 63) / 64, THREADS, 0, stream>>>(
        xbf, ea16, csr_src, csr_dst, wep[0], be[0], aggbf, E);
    fused_mlp_kernel<128, true, false><<<mlp_blocks, THREADS, 0, stream>>>(
        xbf, aggbf, wt1[0], b1[0], wt2[0], b2[0], epsl[0], hbf, (uint4*)aggbf,
        nullptr, nullptr, N);

    // ---- layer 1 (d = 256)
    edge_agg_kernel<256><<<(E + 31) / 32, THREADS, 0, stream>>>(
        hbf, ea16, csr_src, csr_dst, wep[1], be[1], aggbf, E);
    fused_mlp_kernel<256, true, false><<<mlp_blocks, THREADS, 0, stream>>>(
        hbf, aggbf, wt1[1], b1[1], wt2[1], b2[1], epsl[1], hbf, (uint4*)aggbf,
        nullptr, nullptr, N);

    // ---- layer 2 (d = 256): fused pool into hg, no hbf write
    edge_agg_kernel<256><<<(E + 31) / 32, THREADS, 0, stream>>>(
        hbf, ea16, csr_src, csr_dst, wep[2], be[2], aggbf, E);
    fused_mlp_kernel<256, false, true><<<mlp_blocks, THREADS, 0, stream>>>(
        hbf, aggbf, wt1[2], b1[2], wt2[2], b2[2], epsl[2], hbf, (uint4*)aggbf,
        batch, hg, N);

    // ---- Bayesian head (w1buf from prep_kernel)
    head_kernel<<<G, THREADS, 0, stream>>>(
        hg, w1buf, h1_bmu, h1_bls, eps_b1,
        h2_wmu, h2_wls, eps_w2, h2_bmu, h2_bls, eps_b2, out);
}

// Round 19
// 390.963 us; speedup vs baseline: 1.2068x; 1.0013x over previous
//
#include <hip/hip_runtime.h>
#include <hip/hip_bf16.h>
#include <math.h>

// ---------------------------------------------------------------------------
// GINE x3 + global_add_pool + Bayesian head.
// Round 19: edge_agg micro-opt — src pre-scaled by D at staging time
// (kills 16 per-thread v_mul_lo in the gather burst; the scale is computed
// once per edge instead of 128 times). Everything else identical to R18.
// ---------------------------------------------------------------------------

#define THREADS 256

typedef __attribute__((ext_vector_type(8))) short bf16x8;
typedef __attribute__((ext_vector_type(4))) float f32x4;

__device__ __forceinline__ unsigned short f2bf(float x) {
    __hip_bfloat16 h = __float2bfloat16(x);
    return __builtin_bit_cast(unsigned short, h);
}
__device__ __forceinline__ float bflo(unsigned u) {
    return __builtin_bit_cast(float, u << 16);
}
__device__ __forceinline__ float bfhi(unsigned u) {
    return __builtin_bit_cast(float, u & 0xffff0000u);
}
__device__ __forceinline__ float bf2f(unsigned short u) {
    return __builtin_bit_cast(float, (unsigned)u << 16);
}
__device__ __forceinline__ unsigned pk(float a, float b) {
    return (unsigned)f2bf(a) | ((unsigned)f2bf(b) << 16);
}

// ---------------- CSR build: histogram of dst
__global__ __launch_bounds__(THREADS) void hist_kernel(
    const int* __restrict__ ei, int* __restrict__ deg, int E)
{
    int e = blockIdx.x * THREADS + threadIdx.x;
    if (e < E) atomicAdd(&deg[ei[E + e]], 1);
}

// ---------------- CSR build: int4 + wave-shuffle exclusive scan (coalesced).
// Also zeroes deg (=cursor) in-pass for the subsequent fill_kernel.
__global__ __launch_bounds__(1024) void scan_kernel(
    int* __restrict__ deg, int* __restrict__ rowptr, int n)
{
    __shared__ int wsum[16];
    __shared__ int carry_s;
    const int t    = threadIdx.x;
    const int lane = t & 63, wv = t >> 6;
    if (t == 0) carry_s = 0;
    __syncthreads();
    for (int base = 0; base < n; base += 4096) {
        int i = base + t * 4;
        int4 v = make_int4(0, 0, 0, 0);
        if (i + 3 < n) {
            v = *(const int4*)(deg + i);
            *(int4*)(deg + i) = make_int4(0, 0, 0, 0);
        } else if (i < n) {
            v.x = deg[i];                    deg[i] = 0;
            if (i + 1 < n) { v.y = deg[i+1]; deg[i+1] = 0; }
            if (i + 2 < n) { v.z = deg[i+2]; deg[i+2] = 0; }
        }
        int p1 = v.x + v.y, p2 = p1 + v.z, tot = p2 + v.w;
        int incl = tot;
#pragma unroll
        for (int off = 1; off < 64; off <<= 1) {
            int u = __shfl_up(incl, off, 64);
            if (lane >= off) incl += u;
        }
        if (lane == 63) wsum[wv] = incl;
        __syncthreads();
        if (wv == 0) {
            int s = (lane < 16) ? wsum[lane] : 0;
#pragma unroll
            for (int off = 1; off < 16; off <<= 1) {
                int u = __shfl_up(s, off, 64);
                if (lane >= off) s += u;
            }
            if (lane < 16) wsum[lane] = s;
        }
        __syncthreads();
        int waveoff = (wv == 0) ? 0 : wsum[wv - 1];
        int tbase   = carry_s + waveoff + incl - tot;   // exclusive base
        if (i     < n) rowptr[i + 1] = tbase + v.x;
        if (i + 1 < n) rowptr[i + 2] = tbase + p1;
        if (i + 2 < n) rowptr[i + 3] = tbase + p2;
        if (i + 3 < n) rowptr[i + 4] = tbase + tot;
        __syncthreads();
        if (t == 1023) carry_s = carry_s + wsum[15];
        __syncthreads();
    }
    if (t == 0) rowptr[0] = 0;
}

// ---------------- CSR build: scatter edges into slots + ea16 (fused easort)
__global__ __launch_bounds__(THREADS) void fill_kernel(
    const int* __restrict__ ei, const int* __restrict__ rowptr,
    int* __restrict__ cursor, int* __restrict__ csr_src,
    int* __restrict__ csr_dst, const float* __restrict__ edge_attr,
    unsigned short* __restrict__ ea16, int E)
{
    int e = blockIdx.x * THREADS + threadIdx.x;
    if (e >= E) return;
    int s = ei[e], d = ei[E + e];
    int pos  = atomicAdd(&cursor[d], 1);
    int slot = rowptr[d] + pos;
    csr_src[slot] = s;
    csr_dst[slot] = d;
    const float4* a = (const float4*)(edge_attr + (size_t)e * 16);
    float4 a0 = a[0], a1 = a[1], a2 = a[2], a3 = a[3];
    uint4* dst = (uint4*)(ea16 + (size_t)slot * 16);
    dst[0] = make_uint4(pk(a0.x, a0.y), pk(a0.z, a0.w), pk(a1.x, a1.y), pk(a1.z, a1.w));
    dst[1] = make_uint4(pk(a2.x, a2.y), pk(a2.z, a2.w), pk(a3.x, a3.y), pk(a3.z, a3.w));
}

// ---------------- x -> bf16 copy; zeroes aggbf, hg, AND cursor
__global__ __launch_bounds__(THREADS) void xprep_kernel(
    const float* __restrict__ x, unsigned short* __restrict__ xbf, int n4,
    uint4* __restrict__ aggz, int nAgg4,
    float4* __restrict__ hgz, int nHg4,
    uint4* __restrict__ curz, int nCur4)
{
    int i = blockIdx.x * THREADS + threadIdx.x;
    if (i < n4) {
        float4 v = ((const float4*)x)[i];
        uint2 p;
        p.x = pk(v.x, v.y);
        p.y = pk(v.z, v.w);
        ((uint2*)xbf)[i] = p;
    }
    if (i < nAgg4) aggz[i] = make_uint4(0, 0, 0, 0);
    if (i < nHg4)  hgz[i]  = make_float4(0.f, 0.f, 0.f, 0.f);
    if (i < nCur4) curz[i] = make_uint4(0, 0, 0, 0);
}

// ---------------- unified weight prep
struct PrepArgs {
    const float* W[6]; unsigned short* Wt[6]; int K[6];
    const float* mu; const float* ls; const float* eps; float* w1buf;
    const float* We[3]; unsigned short* Wp[3]; int D[3];
};
__global__ __launch_bounds__(THREADS) void prep_kernel(PrepArgs a)
{
    __shared__ float tile[32][33];
    const int z = blockIdx.z;
    const int t = threadIdx.x;

    if (z < 6) {
        const int K = a.K[z];
        const int kb = blockIdx.x * 32;
        if (kb >= K) return;
        const float* W = a.W[z];
        unsigned short* Wt = a.Wt[z];
        const int nb = blockIdx.y * 32;
        const int tx = t & 31, ty = t >> 5;
#pragma unroll
        for (int i = ty; i < 32; i += 8)
            tile[i][tx] = W[(size_t)(kb + i) * 256 + nb + tx];
        __syncthreads();
#pragma unroll
        for (int i = ty; i < 32; i += 8)
            Wt[(size_t)(nb + i) * K + kb + tx] = f2bf(tile[tx][i]);
    } else if (z == 6) {
        int blk = blockIdx.x + blockIdx.y * 8;         // 0..63
#pragma unroll
        for (int c = 0; c < 4; c++) {
            int i = blk * THREADS + t + c * 16384;     // covers 65536
            a.w1buf[i] = a.mu[i] + expf(a.ls[i]) * a.eps[i];
        }
    } else {
        int l = blockIdx.x + blockIdx.y * 8;
        if (l >= 3) return;
        int D = a.D[l];
        if (t >= D) return;
        const float* We = a.We[l];
        unsigned short* Wp = a.Wp[l];
#pragma unroll
        for (int k = 0; k < 16; k++) Wp[t * 32 + k] = f2bf(We[k * D + t]);
#pragma unroll
        for (int k = 16; k < 32; k++) Wp[t * 32 + k] = 0;
    }
}

// ---------------- fused MFMA aggregation (2 feats/lane; src pre-scaled by D)
template<int D>
__global__ __launch_bounds__(THREADS) void edge_agg_kernel(
    const unsigned short* __restrict__ hbf,   // [N][D] bf16
    const unsigned short* __restrict__ ea16,  // [E][16] bf16, CSR order
    const int* __restrict__ csr_src,          // [E]
    const int* __restrict__ csr_dst,          // [E] (non-decreasing)
    const unsigned short* __restrict__ Wtp,   // [D][32] bf16, k>=16 zero
    const float* __restrict__ be,             // [D]
    unsigned short* __restrict__ agg,         // [N][D] bf16, pre-zeroed
    int E)
{
    constexpr int EPB = (D == 128) ? 64 : 32;    // edges per block
    constexpr int LDF = D + 8;                   // padded LDS stride (shorts)
    __shared__ unsigned short msg[EPB * LDF];
    __shared__ int srcD_s[EPB];                  // src * D (pre-scaled)
    __shared__ int dst_x[EPB + 2];               // dst of edges e0-1 .. e0+EPB

    const int t    = threadIdx.x;
    const int e0   = blockIdx.x * EPB;
    const int lane = t & 63, wid = t >> 6;
    const int l15  = lane & 15, lgr = lane >> 4;

    for (int i = t; i < EPB; i += THREADS) {
        int e = e0 + i;
        srcD_s[i] = (e < E) ? (csr_src[e] * D) : 0;   // shift by log2(D)
    }
    for (int i = t; i < EPB + 2; i += THREADS) {
        int e = e0 + i - 1;
        dst_x[i] = (e < 0) ? -2 : ((e < E) ? csr_dst[e] : -1);
    }

    const int fb = (D == 128) ? (wid & 1) * 64 : wid * 64;   // feature base
    const int eb = (D == 128) ? (wid >> 1) * 32 : 0;         // edge base

    bf16x8 af[4];
#pragma unroll
    for (int mf = 0; mf < 4; mf++)
        af[mf] = *(const bf16x8*)(Wtp + (unsigned)(fb + mf * 16 + l15) * 32 + lgr * 8);

    f32x4 acc[4][2];
#pragma unroll
    for (int mf = 0; mf < 4; mf++) {
        int fpos = fb + mf * 16 + lgr * 4;
        float4 bv4 = *(const float4*)(be + fpos);
        f32x4 binit = (f32x4){bv4.x, bv4.y, bv4.z, bv4.w};
        acc[mf][0] = binit;
        acc[mf][1] = binit;
    }

#pragma unroll
    for (int nf = 0; nf < 2; nf++) {
        int er = e0 + eb + nf * 16 + l15;
        bf16x8 bv = (bf16x8){0, 0, 0, 0, 0, 0, 0, 0};
        if (lgr < 2 && er < E)
            bv = *(const bf16x8*)(ea16 + (size_t)er * 16 + lgr * 8);
#pragma unroll
        for (int mf = 0; mf < 4; mf++)
            acc[mf][nf] = __builtin_amdgcn_mfma_f32_16x16x32_bf16(
                af[mf], bv, acc[mf][nf], 0, 0, 0);
    }

#pragma unroll
    for (int nf = 0; nf < 2; nf++) {
        int edge = eb + nf * 16 + l15;
#pragma unroll
        for (int mf = 0; mf < 4; mf++) {
            int fpos = fb + mf * 16 + lgr * 4;
            f32x4 v = acc[mf][nf];
            uint2 p;
            p.x = pk(v[0], v[1]);
            p.y = pk(v[2], v[3]);
            *(uint2*)(&msg[edge * LDF + fpos]) = p;
        }
    }
    __syncthreads();

    constexpr int LPF = D / 2;
    const int f2   = (t & (LPF - 1)) * 2;
    const int win  = t / LPF;
    const int base = win * 16;

    unsigned hv[16], pv[16];
#pragma unroll
    for (int i = 0; i < 16; i++) {
        unsigned off = (unsigned)srcD_s[base + i] + f2;   // pre-scaled: 1 add
        hv[i] = *(const unsigned*)(hbf + off);
        pv[i] = *(const unsigned*)(&msg[(base + i) * LDF + f2]);
    }

    float a0 = 0.f, a1 = 0.f;
    int  cur = dst_x[base + 1];
    bool rs  = (dst_x[base] != cur);

#pragma unroll
    for (int i = 0; i < 16; ++i) {
        int d = dst_x[base + i + 1];
        if (d != cur) {
            if (cur >= 0) {
                unsigned short* ap = agg + ((unsigned)cur * D + f2);
                unsigned v32 = pk(a0, a1);
                if (rs) {
                    *(unsigned*)ap = v32;
                } else {
                    asm volatile("global_atomic_pk_add_bf16 %0, %1, off"
                                 :: "v"(ap), "v"(v32) : "memory");
                }
            }
            a0 = 0.f; a1 = 0.f; rs = true; cur = d;
        }
        a0 += fmaxf(bflo(hv[i]) + bflo(pv[i]), 0.f);
        a1 += fmaxf(bfhi(hv[i]) + bfhi(pv[i]), 0.f);
    }
    if (cur >= 0) {
        bool re = (dst_x[base + 17] != cur);
        unsigned short* ap = agg + ((unsigned)cur * D + f2);
        unsigned v32 = pk(a0, a1);
        if (rs && re) {
            *(unsigned*)ap = v32;
        } else {
            asm volatile("global_atomic_pk_add_bf16 %0, %1, off"
                         :: "v"(ap), "v"(v32) : "memory");
        }
    }
}

// ---------------- fused node MLP v3 (+ optional agg-zero, optional pool)
template<int KIN, bool ZERO, bool POOL>
__global__ __launch_bounds__(THREADS) void fused_mlp_kernel(
    const unsigned short* __restrict__ hin,   // [nrows, KIN] bf16
    const unsigned short* __restrict__ agg,   // [nrows, KIN] bf16
    const unsigned short* __restrict__ Wt1,   // [256, KIN] bf16
    const float* __restrict__ b1,             // [256]
    const unsigned short* __restrict__ Wt2,   // [256, 256] bf16
    const float* __restrict__ b2,             // [256]
    const float* __restrict__ epsp,           // [1]
    unsigned short* __restrict__ out,         // [nrows, 256] bf16 (!POOL)
    uint4* __restrict__ aggz,                 // agg as uint4 (zero target)
    const int* __restrict__ batch,            // [nrows] (POOL)
    float* __restrict__ hg,                   // [G, 256] f32 (POOL)
    int nrows)
{
    constexpr int LDT = 264;                  // 256 + 8 shorts
    __shared__ short Buf[64 * LDT];           // A panel -> Tmp -> pool buffer
    __shared__ int bat[64];

    const int t    = threadIdx.x;
    const int lane = t & 63;
    const int wid  = t >> 6;                  // wave col-stripe
    const int l15  = lane & 15, lgr = lane >> 4;
    const int r0   = blockIdx.x * 64;

    const float scale = 1.0f + epsp[0];

    constexpr int RU = KIN / 8;               // uint4 per row
#pragma unroll
    for (int c = 0; c < (64 * RU) / THREADS; c++) {
        int idx = t + c * THREADS;
        int r   = idx / RU;
        int kq  = idx % RU;
        int row = r0 + r;
        uint4 o = make_uint4(0, 0, 0, 0);
        if (row < nrows) {
            size_t g = (size_t)row * KIN + kq * 8;
            uint4 hv = *(const uint4*)(hin + g);
            uint4 av = *(const uint4*)(agg + g);
            o.x = pk(scale * bflo(hv.x) + bflo(av.x),
                     scale * bfhi(hv.x) + bfhi(av.x));
            o.y = pk(scale * bflo(hv.y) + bflo(av.y),
                     scale * bfhi(hv.y) + bfhi(av.y));
            o.z = pk(scale * bflo(hv.z) + bflo(av.z),
                     scale * bfhi(hv.z) + bfhi(av.z));
            o.w = pk(scale * bflo(hv.w) + bflo(av.w),
                     scale * bfhi(hv.w) + bfhi(av.w));
        }
        *(uint4*)(&Buf[r * LDT + kq * 8]) = o;
    }
    if (POOL && t < 64) {
        int row = r0 + t;
        bat[t] = (row < nrows) ? batch[row] : -1;
    }
    __syncthreads();

    if (ZERO) {
        const unsigned aggTot8 = (unsigned)nrows * 32;   // uint4 units
        const uint4 zz = make_uint4(0, 0, 0, 0);
        if (KIN == 256) {
            unsigned b8 = (unsigned)blockIdx.x * 2048;
#pragma unroll
            for (int c = 0; c < 8; c++) {
                unsigned idx = b8 + t + c * THREADS;
                if (idx < aggTot8) aggz[idx] = zz;
            }
        } else {
            unsigned own  = (unsigned)blockIdx.x * 1024;
            unsigned tail = ((unsigned)gridDim.x + (unsigned)blockIdx.x) * 1024;
#pragma unroll
            for (int c = 0; c < 4; c++) {
                unsigned i1 = own + t + c * THREADS;
                if (i1 < aggTot8) aggz[i1] = zz;
                unsigned i2 = tail + t + c * THREADS;
                if (i2 < aggTot8) aggz[i2] = zz;
            }
        }
    }

    // ---- GEMM1: A from Buf (barrier-free), B direct from global
    f32x4 acc[4][4];
#pragma unroll
    for (int nf = 0; nf < 4; nf++) {
        float bv = b1[wid * 64 + nf * 16 + l15];
#pragma unroll
        for (int mf = 0; mf < 4; mf++)
            acc[mf][nf] = (f32x4){bv, bv, bv, bv};
    }

#pragma unroll
    for (int k0 = 0; k0 < KIN; k0 += 64) {
#pragma unroll
        for (int ks = 0; ks < 2; ks++) {
            bf16x8 afr[4], bfr[4];
#pragma unroll
            for (int nf = 0; nf < 4; nf++)
                bfr[nf] = *(const bf16x8*)(Wt1 +
                    (size_t)(wid * 64 + nf * 16 + l15) * KIN + k0 + ks * 32 + lgr * 8);
#pragma unroll
            for (int mf = 0; mf < 4; mf++)
                afr[mf] = *(const bf16x8*)(&Buf[(mf * 16 + l15) * LDT + k0 + ks * 32 + lgr * 8]);
#pragma unroll
            for (int mf = 0; mf < 4; mf++)
#pragma unroll
                for (int nf = 0; nf < 4; nf++)
                    acc[mf][nf] = __builtin_amdgcn_mfma_f32_16x16x32_bf16(
                        afr[mf], bfr[nf], acc[mf][nf], 0, 0, 0);
        }
    }
    __syncthreads();   // all waves done reading the A panel

    // ---- relu + write z (Tmp) into Buf, re-init acc with b2
#pragma unroll
    for (int nf = 0; nf < 4; nf++) {
        int col = wid * 64 + nf * 16 + l15;
#pragma unroll
        for (int mf = 0; mf < 4; mf++) {
            f32x4 v = acc[mf][nf];
#pragma unroll
            for (int r = 0; r < 4; r++) {
                int row = mf * 16 + lgr * 4 + r;
                Buf[row * LDT + col] = (short)f2bf(fmaxf(v[r], 0.f));
            }
        }
    }
#pragma unroll
    for (int nf = 0; nf < 4; nf++) {
        float bv = b2[wid * 64 + nf * 16 + l15];
#pragma unroll
        for (int mf = 0; mf < 4; mf++)
            acc[mf][nf] = (f32x4){bv, bv, bv, bv};
    }
    __syncthreads();

    // ---- GEMM2: A = Buf (z), B = Wt2 direct from global; barrier-free
#pragma unroll
    for (int k0 = 0; k0 < 256; k0 += 64) {
#pragma unroll
        for (int ks = 0; ks < 2; ks++) {
            bf16x8 afr[4], bfr[4];
#pragma unroll
            for (int nf = 0; nf < 4; nf++)
                bfr[nf] = *(const bf16x8*)(Wt2 +
                    (size_t)(wid * 64 + nf * 16 + l15) * 256 + k0 + ks * 32 + lgr * 8);
#pragma unroll
            for (int mf = 0; mf < 4; mf++)
                afr[mf] = *(const bf16x8*)(&Buf[(mf * 16 + l15) * LDT + k0 + ks * 32 + lgr * 8]);
#pragma unroll
            for (int mf = 0; mf < 4; mf++)
#pragma unroll
                for (int nf = 0; nf < 4; nf++)
                    acc[mf][nf] = __builtin_amdgcn_mfma_f32_16x16x32_bf16(
                        afr[mf], bfr[nf], acc[mf][nf], 0, 0, 0);
        }
    }

    if (!POOL) {
#pragma unroll
        for (int nf = 0; nf < 4; nf++) {
            int col = wid * 64 + nf * 16 + l15;
#pragma unroll
            for (int mf = 0; mf < 4; mf++) {
                f32x4 v = acc[mf][nf];
#pragma unroll
                for (int r = 0; r < 4; r++) {
                    int row = r0 + mf * 16 + lgr * 4 + r;
                    if (row < nrows)
                        out[(size_t)row * 256 + col] = f2bf(fmaxf(v[r], 0.f));
                }
            }
        }
    } else {
        __syncthreads();   // all waves done reading z from Buf
#pragma unroll
        for (int nf = 0; nf < 4; nf++) {
            int col = wid * 64 + nf * 16 + l15;
#pragma unroll
            for (int mf = 0; mf < 4; mf++) {
                f32x4 v = acc[mf][nf];
#pragma unroll
                for (int r = 0; r < 4; r++) {
                    int row = mf * 16 + lgr * 4 + r;
                    Buf[row * LDT + col] = (short)f2bf(fmaxf(v[r], 0.f));
                }
            }
        }
        __syncthreads();

        float a = 0.f;
        int cur = bat[0];
        for (int r = 0; r < 64; ++r) {
            int b = bat[r];
            if (b != cur) {
                if (cur >= 0) atomicAdd(&hg[(size_t)cur * 256 + t], a);
                a = 0.f; cur = b;
            }
            a += bf2f((unsigned short)Buf[r * LDT + t]);
        }
        if (cur >= 0) atomicAdd(&hg[(size_t)cur * 256 + t], a);
    }
}

// ---------------- head
__global__ __launch_bounds__(THREADS) void head_kernel(
    const float* __restrict__ hg,
    const float* __restrict__ w1,
    const float* __restrict__ h1_bmu, const float* __restrict__ h1_bls,
    const float* __restrict__ eps_b1,
    const float* __restrict__ h2_wmu, const float* __restrict__ h2_wls,
    const float* __restrict__ eps_w2,
    const float* __restrict__ h2_bmu, const float* __restrict__ h2_bls,
    const float* __restrict__ eps_b2,
    float* __restrict__ out)
{
    __shared__ float x_s[256];
    __shared__ float red[256];
    const int t = threadIdx.x;
    const int g = blockIdx.x;

    x_s[t] = hg[(size_t)g * 256 + t];
    __syncthreads();

    float acc = h1_bmu[t] + expf(h1_bls[t]) * eps_b1[t];
    for (int kk = 0; kk < 256; kk++) acc += x_s[kk] * w1[kk * 256 + t];
    float h1v = acc / (1.f + expf(-acc));

    float w2a = h2_wmu[t * 2 + 0] + expf(h2_wls[t * 2 + 0]) * eps_w2[t * 2 + 0];
    float w2b = h2_wmu[t * 2 + 1] + expf(h2_wls[t * 2 + 1]) * eps_w2[t * 2 + 1];

    red[t] = h1v * w2a;
    __syncthreads();
    for (int s = 128; s > 0; s >>= 1) {
        if (t < s) red[t] += red[t + s];
        __syncthreads();
    }
    if (t == 0) out[(size_t)g * 2 + 0] = red[0] + h2_bmu[0] + expf(h2_bls[0]) * eps_b2[0];
    __syncthreads();

    red[t] = h1v * w2b;
    __syncthreads();
    for (int s = 128; s > 0; s >>= 1) {
        if (t < s) red[t] += red[t + s];
        __syncthreads();
    }
    if (t == 0) out[(size_t)g * 2 + 1] = red[0] + h2_bmu[1] + expf(h2_bls[1]) * eps_b2[1];
}

// ---------------------------------------------------------------------------
extern "C" void kernel_launch(void* const* d_in, const int* in_sizes, int n_in,
                              void* d_out, int out_size, void* d_ws, size_t ws_size,
                              hipStream_t stream)
{
    const float* x         = (const float*)d_in[0];
    const float* edge_attr = (const float*)d_in[1];
    const int*   ei        = (const int*)d_in[2];
    const int*   batch     = (const int*)d_in[3];

    const float* We[3]  = { (const float*)d_in[4],  (const float*)d_in[11], (const float*)d_in[18] };
    const float* be[3]  = { (const float*)d_in[5],  (const float*)d_in[12], (const float*)d_in[19] };
    const float* W1[3]  = { (const float*)d_in[6],  (const float*)d_in[13], (const float*)d_in[20] };
    const float* b1[3]  = { (const float*)d_in[7],  (const float*)d_in[14], (const float*)d_in[21] };
    const float* W2[3]  = { (const float*)d_in[8],  (const float*)d_in[15], (const float*)d_in[22] };
    const float* b2[3]  = { (const float*)d_in[9],  (const float*)d_in[16], (const float*)d_in[23] };
    const float* epsl[3]= { (const float*)d_in[10], (const float*)d_in[17], (const float*)d_in[24] };

    const float* h1_wmu = (const float*)d_in[25];
    const float* h1_wls = (const float*)d_in[26];
    const float* h1_bmu = (const float*)d_in[27];
    const float* h1_bls = (const float*)d_in[28];
    const float* h2_wmu = (const float*)d_in[29];
    const float* h2_wls = (const float*)d_in[30];
    const float* h2_bmu = (const float*)d_in[31];
    const float* h2_bls = (const float*)d_in[32];
    const float* eps_w1 = (const float*)d_in[33];
    const float* eps_b1 = (const float*)d_in[34];
    const float* eps_w2 = (const float*)d_in[35];
    const float* eps_b2 = (const float*)d_in[36];

    const int N = in_sizes[0] / 128;
    const int E = in_sizes[1] / 16;
    const int G = out_size / 2;

    // ---- carve workspace (256B aligned chunks)
    uintptr_t p = (uintptr_t)d_ws;
    auto carve = [&](size_t bytes) -> void* {
        void* r = (void*)p;
        p = (p + bytes + 255) & ~(uintptr_t)255;
        return r;
    };
    float* hg      = (float*)carve((size_t)G * 256 * 4);
    float* w1buf   = (float*)carve(256 * 256 * 4);
    int*   rowptr  = (int*)carve((size_t)(N + 1) * 4);
    int*   cursor  = (int*)carve((size_t)(N + 4) * 4);   // +pad for uint4 zeroing
    int*   csr_src = (int*)carve((size_t)E * 4);
    int*   csr_dst = (int*)carve((size_t)E * 4);
    unsigned short* aggbf = (unsigned short*)carve(((size_t)N * 256 + 16384) * 2);
    unsigned short* ea16  = (unsigned short*)carve((size_t)E * 16 * 2);
    unsigned short* hbf   = (unsigned short*)carve((size_t)N * 256 * 2);
    unsigned short* xbf   = (unsigned short*)carve((size_t)N * 128 * 2);
    unsigned short* wep[3];
    wep[0] = (unsigned short*)carve(128 * 32 * 2);
    wep[1] = (unsigned short*)carve(256 * 32 * 2);
    wep[2] = (unsigned short*)carve(256 * 32 * 2);
    unsigned short* wt1[3], *wt2[3];
    wt1[0] = (unsigned short*)carve(256 * 128 * 2);
    for (int l = 0; l < 3; l++) {
        if (l) wt1[l] = (unsigned short*)carve(256 * 256 * 2);
        wt2[l] = (unsigned short*)carve(256 * 256 * 2);
    }

    const int eblocks    = (E + THREADS - 1) / THREADS;
    const int mlp_blocks = (N + 63) / 64;

    float* out = (float*)d_out;

    // ---- xprep first: converts x, zeroes aggbf + hg + cursor (no memset)
    xprep_kernel<<<(N * 32 + THREADS - 1) / THREADS, THREADS, 0, stream>>>(
        x, xbf, N * 32, (uint4*)aggbf, N * 32, (float4*)hg, G * 64,
        (uint4*)cursor, (N + 3) / 4);

    // ---- CSR build: hist -> scan (zeroes cursor) -> fill
    hist_kernel<<<eblocks, THREADS, 0, stream>>>(ei, cursor, E);
    scan_kernel<<<1, 1024, 0, stream>>>(cursor, rowptr, N);
    fill_kernel<<<eblocks, THREADS, 0, stream>>>(
        ei, rowptr, cursor, csr_src, csr_dst, edge_attr, ea16, E);

    // ---- unified weight prep (1 dispatch)
    PrepArgs pa;
    pa.W[0] = W1[0]; pa.Wt[0] = wt1[0]; pa.K[0] = 128;
    pa.W[1] = W2[0]; pa.Wt[1] = wt2[0]; pa.K[1] = 256;
    pa.W[2] = W1[1]; pa.Wt[2] = wt1[1]; pa.K[2] = 256;
    pa.W[3] = W2[1]; pa.Wt[3] = wt2[1]; pa.K[3] = 256;
    pa.W[4] = W1[2]; pa.Wt[4] = wt1[2]; pa.K[4] = 256;
    pa.W[5] = W2[2]; pa.Wt[5] = wt2[2]; pa.K[5] = 256;
    pa.mu = h1_wmu; pa.ls = h1_wls; pa.eps = eps_w1; pa.w1buf = w1buf;
    for (int l = 0; l < 3; l++) { pa.We[l] = We[l]; pa.Wp[l] = wep[l]; }
    pa.D[0] = 128; pa.D[1] = 256; pa.D[2] = 256;
    prep_kernel<<<dim3(8, 8, 8), THREADS, 0, stream>>>(pa);

    // ---- layer 0 (d = 128, h = xbf)
    edge_agg_kernel<128><<<(E + 63) / 64, THREADS, 0, stream>>>(
        xbf, ea16, csr_src, csr_dst, wep[0], be[0], aggbf, E);
    fused_mlp_kernel<128, true, false><<<mlp_blocks, THREADS, 0, stream>>>(
        xbf, aggbf, wt1[0], b1[0], wt2[0], b2[0], epsl[0], hbf, (uint4*)aggbf,
        nullptr, nullptr, N);

    // ---- layer 1 (d = 256)
    edge_agg_kernel<256><<<(E + 31) / 32, THREADS, 0, stream>>>(
        hbf, ea16, csr_src, csr_dst, wep[1], be[1], aggbf, E);
    fused_mlp_kernel<256, true, false><<<mlp_blocks, THREADS, 0, stream>>>(
        hbf, aggbf, wt1[1], b1[1], wt2[1], b2[1], epsl[1], hbf, (uint4*)aggbf,
        nullptr, nullptr, N);

    // ---- layer 2 (d = 256): fused pool into hg, no hbf write
    edge_agg_kernel<256><<<(E + 31) / 32, THREADS, 0, stream>>>(
        hbf, ea16, csr_src, csr_dst, wep[2], be[2], aggbf, E);
    fused_mlp_kernel<256, false, true><<<mlp_blocks, THREADS, 0, stream>>>(
        hbf, aggbf, wt1[2], b1[2], wt2[2], b2[2], epsl[2], hbf, (uint4*)aggbf,
        batch, hg, N);

    // ---- Bayesian head (w1buf from prep_kernel)
    head_kernel<<<G, THREADS, 0, stream>>>(
        hg, w1buf, h1_bmu, h1_bls, eps_b1,
        h2_wmu, h2_wls, eps_w2, h2_bmu, h2_bls, eps_b2, out);
}